// Round 12
// baseline (5518.259 us; speedup 1.0000x reference)
//
#include <hip/hip_runtime.h>
#include <math.h>
#include <stdint.h>

// ScalarSGC: 2 layers of  x <- elu( scalars[l] * (A @ x) )
// R12 = R11 with ONE variable changed: LDS f32 accumulation via
// __hip_atomic_fetch_add(..., __ATOMIC_RELAXED, __HIP_MEMORY_SCOPE_WORKGROUP)
// -- weakest ordering + narrowest scope, the only remaining source-level knob
// that can let LLVM emit bare fire-and-forget ds_add_f32.  R10 (atomicAdd)
// and R11 (unsafeAtomicAdd) produced BYTE-IDENTICAL serialization (~107
// cyc/op, VALUBusy 1.6%): the cost is ordering/scope-induced waits, not CAS
// vs native.  If this probe fails too, the bucket-LDS branch is closed and
// R9 (412.1us) is the declared plateau.
// Structure: edges sorted by (128-row bucket, colseg); one block per bucket
// sweeps colseg-ordered edges (blocks ~equal size -> rough lockstep ->
// instantaneous gather working set ~2-4MB ~ per-XCD L2).

#define D_FEAT 128
#define D2     64          // feature pairs per row
#define SCAN_TILE 1024

#define PB 256             // partition/count blocks
#define PT 1024            // threads per partition/count block
#define RB_BITS 7          // rows per bucket = 128
#define SROWS 128          // rows per bucket
#define RSTRIDE 144        // f32 stride per row in LDS (16 lanes x 9 words)
#define COL_BITS 17        // N = 100000 < 2^17
#define COL_MASK ((1 << COL_BITS) - 1)
#define SEG_SHIFT 13       // colseg = col >> 13 (13 segs x 2MB of table)

__device__ __forceinline__ uint32_t f2bf(float f) {
    uint32_t u = __float_as_uint(f);
    return (u + 0x7FFFu + ((u >> 16) & 1u)) >> 16;   // RNE
}
__device__ __forceinline__ float bf_lo(uint32_t w) { return __uint_as_float(w << 16); }
__device__ __forceinline__ float bf_hi(uint32_t w) { return __uint_as_float(w & 0xFFFF0000u); }

// ---------------- f32 -> bf16 conversion (2 elems/thread) ----------------
__global__ void convert_kernel(const float2* __restrict__ xin, uint32_t* __restrict__ xbf, int n2) {
    int i = blockIdx.x * blockDim.x + threadIdx.x;
    if (i < n2) {
        float2 f = xin[i];
        xbf[i] = f2bf(f.x) | (f2bf(f.y) << 16);
    }
}

// ---------------- phase 1: coarse per-(bucket,block) counts, LDS only ----------------
__global__ __launch_bounds__(PT) void coarse_count_kernel(const int* __restrict__ row,
                                                          int* __restrict__ cnt,
                                                          int E, int nbuck) {
    __shared__ int hist[1024];
    const int t = threadIdx.x;
    hist[t] = 0;
    __syncthreads();
    const int stride = PB * PT;
    const int gid = blockIdx.x * PT + t;
    const int E4 = E >> 2;
    const int4* __restrict__ r4 = (const int4*)row;
    for (int i = gid; i < E4; i += stride) {
        int4 r = r4[i];
        atomicAdd(&hist[r.x >> RB_BITS], 1);
        atomicAdd(&hist[r.y >> RB_BITS], 1);
        atomicAdd(&hist[r.z >> RB_BITS], 1);
        atomicAdd(&hist[r.w >> RB_BITS], 1);
    }
    for (int i = (E4 << 2) + gid; i < E; i += stride)   // tail (E%4 != 0)
        atomicAdd(&hist[row[i] >> RB_BITS], 1);
    __syncthreads();
    if (t < nbuck) cnt[t * PB + blockIdx.x] = hist[t];
}

// ---------------- scan phase 1: per-tile exclusive scan + tile sums ----------------
__global__ __launch_bounds__(SCAN_TILE) void scan1_kernel(const int* __restrict__ counts,
                                                          int* __restrict__ excl,
                                                          int* __restrict__ tileSums, int n) {
    __shared__ int wsum[16];
    const int tid  = threadIdx.x;
    const int lane = tid & 63;
    const int wave = tid >> 6;
    const int i    = blockIdx.x * SCAN_TILE + tid;

    int v = (i < n) ? counts[i] : 0;
    int incl = v;
    #pragma unroll
    for (int off = 1; off < 64; off <<= 1) {
        int t = __shfl_up(incl, off, 64);
        if (lane >= off) incl += t;
    }
    if (lane == 63) wsum[wave] = incl;
    __syncthreads();
    if (wave == 0) {
        int s = (lane < 16) ? wsum[lane] : 0;
        #pragma unroll
        for (int off = 1; off < 16; off <<= 1) {
            int t = __shfl_up(s, off, 64);
            if (lane >= off) s += t;
        }
        if (lane < 16) wsum[lane] = s;
    }
    __syncthreads();
    int wbase = (wave == 0) ? 0 : wsum[wave - 1];
    if (i < n) excl[i] = wbase + (incl - v);
    if (tid == 0) tileSums[blockIdx.x] = wsum[15];
}

// ---------------- scan phase 2: scan tile sums (single block, up to 1024) ----------------
__global__ __launch_bounds__(1024) void scan2_kernel(const int* __restrict__ tileSums,
                                                     int* __restrict__ tileBase,
                                                     int* __restrict__ total_out, int nb) {
    __shared__ int buf[1024];
    const int tid = threadIdx.x;
    int v = (tid < nb) ? tileSums[tid] : 0;
    buf[tid] = v;
    __syncthreads();
    #pragma unroll
    for (int off = 1; off < 1024; off <<= 1) {
        int t = (tid >= off) ? buf[tid - off] : 0;
        __syncthreads();
        buf[tid] += t;
        __syncthreads();
    }
    if (tid < nb) tileBase[tid] = buf[tid] - v;
    if (tid == nb - 1) *total_out = buf[tid];
}

// ---------------- phase 2: partition edges into 782 buckets (LDS cursors) ------
__global__ __launch_bounds__(PT) void partition_kernel(const int* __restrict__ row,
                                                       const int* __restrict__ col,
                                                       const float* __restrict__ val,
                                                       const int* __restrict__ cnt,
                                                       const int* __restrict__ tileBase,
                                                       int2* __restrict__ pack2,
                                                       int E, int nbuck) {
    __shared__ int cur[1024];
    const int t = threadIdx.x;
    if (t < nbuck) {
        int idx = t * PB + blockIdx.x;
        cur[t] = cnt[idx] + tileBase[idx >> 10];
    }
    __syncthreads();
    const int stride = PB * PT;
    const int gid = blockIdx.x * PT + t;
    const int E4 = E >> 2;
    const int4*   __restrict__ r4 = (const int4*)row;
    const int4*   __restrict__ c4 = (const int4*)col;
    const float4* __restrict__ v4 = (const float4*)val;
    for (int i = gid; i < E4; i += stride) {
        int4   r = r4[i];
        int4   c = c4[i];
        float4 v = v4[i];
        int p0 = atomicAdd(&cur[r.x >> RB_BITS], 1);
        int p1 = atomicAdd(&cur[r.y >> RB_BITS], 1);
        int p2 = atomicAdd(&cur[r.z >> RB_BITS], 1);
        int p3 = atomicAdd(&cur[r.w >> RB_BITS], 1);
        pack2[p0] = make_int2(c.x | ((r.x & (SROWS - 1)) << COL_BITS), __float_as_int(v.x));
        pack2[p1] = make_int2(c.y | ((r.y & (SROWS - 1)) << COL_BITS), __float_as_int(v.y));
        pack2[p2] = make_int2(c.z | ((r.z & (SROWS - 1)) << COL_BITS), __float_as_int(v.z));
        pack2[p3] = make_int2(c.w | ((r.w & (SROWS - 1)) << COL_BITS), __float_as_int(v.w));
    }
    for (int i = (E4 << 2) + gid; i < E; i += stride) {  // tail
        int r = row[i];
        int pos = atomicAdd(&cur[r >> RB_BITS], 1);
        pack2[pos] = make_int2(col[i] | ((r & (SROWS - 1)) << COL_BITS),
                               __float_as_int(val[i]));
    }
}

// ---------------- phase 3: per-bucket 16-bin colseg split ----------------
__global__ __launch_bounds__(256) void fineseg_kernel(const int* __restrict__ cnt,
                                                      const int* __restrict__ tileBase,
                                                      const int2* __restrict__ pack2,
                                                      int2* __restrict__ pack,
                                                      int E, int nbuck) {
    __shared__ int wcnt[4][16];
    __shared__ int wbase[4][16];
    const int b    = blockIdx.x;
    const int t    = threadIdx.x;
    const int wave = t >> 6;
    const int lane = t & 63;
    const int start = cnt[b << 8] + tileBase[b >> 2];
    const int end   = (b == nbuck - 1) ? E : (cnt[(b + 1) << 8] + tileBase[(b + 1) >> 2]);
    const int n = end - start;

    if (t < 64) ((int*)wcnt)[t] = 0;
    __syncthreads();

    for (int i = t; i < n; i += 256) {
        int key = pack2[start + i].x;
        int seg = (key & COL_MASK) >> SEG_SHIFT;
        atomicAdd(&wcnt[wave][seg], 1);
    }
    __syncthreads();

    if (wave == 0) {
        // scan 64 counters in seg-major, wave-minor order
        const int s_ = lane >> 2, w_ = lane & 3;
        int v = wcnt[w_][s_];
        int incl = v;
        #pragma unroll
        for (int off = 1; off < 64; off <<= 1) {
            int tv = __shfl_up(incl, off, 64);
            if (lane >= off) incl += tv;
        }
        wbase[w_][s_] = incl - v;
    }
    __syncthreads();

    for (int i = t; i < n; i += 256) {
        int2 wd = pack2[start + i];
        int seg = (wd.x & COL_MASK) >> SEG_SHIFT;
        int p = atomicAdd(&wbase[wave][seg], 1);
        pack[start + p] = wd;
    }
}

// ---------------- bucket-LDS SpMM + scalar scale + ELU ----------------
// Block = 1024 threads = 64 groups of 16 lanes; block owns a 128-row bucket
// with f32 accumulators in LDS.  Group processes one edge: 16 lanes gather
// the full 256B source row (uint4 each), multiply by edge val, and add into
// the bucket accumulator via RELAXED WORKGROUP-scope fetch_add (weakest
// expressible -> candidate for bare ds_add_f32 with no waits).
template <int OUT_BF16>
__global__ __launch_bounds__(1024) void spmm_bucket_kernel(
    const int* __restrict__ cnt, const int* __restrict__ tileBase,
    const int2* __restrict__ pack, const uint32_t* __restrict__ xin,
    void* __restrict__ xout, const float* __restrict__ scalars,
    int layer, int N, int E, int nbuck) {
    extern __shared__ float acc[];                  // SROWS * RSTRIDE floats
    const int b = blockIdx.x;
    const int t = threadIdx.x;
    const int start = cnt[b << 8] + tileBase[b >> 2];
    const int end   = (b == nbuck - 1) ? E : (cnt[(b + 1) << 8] + tileBase[(b + 1) >> 2]);

    for (int i = t; i < SROWS * RSTRIDE; i += 1024) acc[i] = 0.f;
    __syncthreads();

    const int grp = t >> 4;          // 0..63: group = one edge slot
    const int sub = t & 15;          // 16B chunk within the source row
    const uint4* __restrict__ xin4 = (const uint4*)xin;
    const uint64_t* __restrict__ pk = (const uint64_t*)pack;

    #define LADD(P, V) __hip_atomic_fetch_add((P), (V), __ATOMIC_RELAXED, \
                                              __HIP_MEMORY_SCOPE_WORKGROUP)
    #define ADDS(W, VAL, DST)                                              \
        LADD((DST) + 0, (VAL) * bf_lo((W).x));                             \
        LADD((DST) + 1, (VAL) * bf_hi((W).x));                             \
        LADD((DST) + 2, (VAL) * bf_lo((W).y));                             \
        LADD((DST) + 3, (VAL) * bf_hi((W).y));                             \
        LADD((DST) + 4, (VAL) * bf_lo((W).z));                             \
        LADD((DST) + 5, (VAL) * bf_hi((W).z));                             \
        LADD((DST) + 6, (VAL) * bf_lo((W).w));                             \
        LADD((DST) + 7, (VAL) * bf_hi((W).w));

    int e = start + grp;
    for (; e + 64 < end; e += 128) {     // 2 edges (2KB of gather) in flight
        uint64_t q0 = pk[e];
        uint64_t q1 = pk[e + 64];
        uint32_t k0 = (uint32_t)q0, k1 = (uint32_t)q1;
        float    v0 = __uint_as_float((uint32_t)(q0 >> 32));
        float    v1 = __uint_as_float((uint32_t)(q1 >> 32));
        uint4 w0 = xin4[(((uint32_t)(k0 & COL_MASK)) << 4) + sub];
        uint4 w1 = xin4[(((uint32_t)(k1 & COL_MASK)) << 4) + sub];
        float* d0 = &acc[(k0 >> COL_BITS) * RSTRIDE + sub * 9];
        float* d1 = &acc[(k1 >> COL_BITS) * RSTRIDE + sub * 9];
        ADDS(w0, v0, d0);
        ADDS(w1, v1, d1);
    }
    if (e < end) {
        uint64_t q = pk[e];
        uint32_t k = (uint32_t)q;
        float    v = __uint_as_float((uint32_t)(q >> 32));
        uint4 w = xin4[(((uint32_t)(k & COL_MASK)) << 4) + sub];
        float* d = &acc[(k >> COL_BITS) * RSTRIDE + sub * 9];
        ADDS(w, v, d);
    }
    #undef ADDS
    #undef LADD
    __syncthreads();

    // epilogue: scale + ELU + coalesced store (feature f at lr*144+(f>>3)*9+(f&7))
    const float s = scalars[layer];
    const int rbase = b * SROWS;
    for (int idx = t; idx < SROWS * 64; idx += 1024) {
        int lr = idx >> 6, p = idx & 63;
        int r = rbase + lr;
        if (r < N) {
            int off = lr * RSTRIDE + (p >> 2) * 9 + ((2 * p) & 7);
            float x0 = acc[off] * s;
            float x1 = acc[off + 1] * s;
            x0 = (x0 > 0.f) ? x0 : (expf(x0) - 1.f);
            x1 = (x1 > 0.f) ? x1 : (expf(x1) - 1.f);
            if (OUT_BF16) {
                ((uint32_t*)xout)[(size_t)r * D2 + p] = f2bf(x0) | (f2bf(x1) << 16);
            } else {
                ((float2*)xout)[(size_t)r * D2 + p] = make_float2(x0, x1);
            }
        }
    }
}

extern "C" void kernel_launch(void* const* d_in, const int* in_sizes, int n_in,
                              void* d_out, int out_size, void* d_ws, size_t ws_size,
                              hipStream_t stream) {
    const float* x         = (const float*)d_in[0];
    const int*   edge_row  = (const int*)d_in[1];
    const int*   edge_col  = (const int*)d_in[2];
    const float* edge_vals = (const float*)d_in[3];
    const float* scalars   = (const float*)d_in[4];

    const int N = in_sizes[0] / D_FEAT;                      // 100000
    const int E = in_sizes[1];                               // 3200000
    const int nbuck = (N + SROWS - 1) >> RB_BITS;            // 782
    const int M = nbuck * PB;                                // 200192
    const int NB = (M + SCAN_TILE - 1) / SCAN_TILE;          // 196

    // ---- workspace bump allocator (256B aligned) ----
    char*  ws  = (char*)d_ws;
    size_t off = 0;
    auto alloc = [&](size_t bytes) -> void* {
        off = (off + 255) & ~(size_t)255;
        void* p = ws + off;
        off += bytes;
        return p;
    };
    int*      cnt      = (int*)alloc((size_t)(M + 1) * sizeof(int));
    int*      tileSums = (int*)alloc((size_t)NB * sizeof(int));
    int*      tileBase = (int*)alloc((size_t)NB * sizeof(int));
    int2*     pack2    = (int2*)alloc((size_t)E * sizeof(int2));
    int2*     pack     = (int2*)alloc((size_t)E * sizeof(int2));
    uint32_t* xbf      = (uint32_t*)alloc((size_t)N * D2 * sizeof(uint32_t));
    uint32_t* hbf      = (uint32_t*)pack2;   // alias: pack2 dead after fineseg
    (void)ws_size;

    // ---- bf16 table + CSR build (no global atomics) ----
    convert_kernel<<<(N * D2 + 255) / 256, 256, 0, stream>>>((const float2*)x, xbf, N * D2);
    coarse_count_kernel<<<PB, PT, 0, stream>>>(edge_row, cnt, E, nbuck);
    scan1_kernel<<<NB, SCAN_TILE, 0, stream>>>(cnt, cnt, tileSums, M);
    scan2_kernel<<<1, 1024, 0, stream>>>(tileSums, tileBase, cnt + M, NB);
    partition_kernel<<<PB, PT, 0, stream>>>(edge_row, edge_col, edge_vals, cnt, tileBase,
                                            pack2, E, nbuck);
    fineseg_kernel<<<nbuck, 256, 0, stream>>>(cnt, tileBase, pack2, pack, E, nbuck);

    // ---- layer 1: xbf -> hbf (bf16), layer 2: hbf -> d_out (f32) ----
    const size_t lds_bytes = (size_t)SROWS * RSTRIDE * sizeof(float);   // 73728
    spmm_bucket_kernel<1><<<nbuck, 1024, lds_bytes, stream>>>(
        cnt, tileBase, pack, xbf, hbf, scalars, 0, N, E, nbuck);
    spmm_bucket_kernel<0><<<nbuck, 1024, lds_bytes, stream>>>(
        cnt, tileBase, pack, hbf, (void*)d_out, scalars, 1, N, E, nbuck);
}

// Round 13
// 411.864 us; speedup vs baseline: 13.3983x; 13.3983x over previous
//
#include <hip/hip_runtime.h>
#include <math.h>
#include <stdint.h>

// ScalarSGC: 2 layers of  x <- elu( scalars[l] * (A @ x) )
// FINAL (R13 = R9, twice-measured 412.1/412.8us): best-known configuration.
// CSR built per call with ZERO global atomics: coarse LDS count -> 3-phase
// scan -> LDS-cursor partition (196 sequential write streams per block) ->
// per-bucket fine sort with full-bucket LDS edge cache.  count/partition use
// int4-batched edge loads (4 independent LDS-atomic->store chains/iteration).
// SpMM: wave-per-row, 4 lane-groups of 16 lanes each gather a FULL 256B
// source row via global_load_dwordx4 (1KB/instruction = 4 edges),
// scalarized pack reads, fused scale + ELU.
// Ceiling notes (session evidence):
//  - spmm pinned at ~3.9TB/s L2-miss path, FETCH ~371MB, across all gather
//    structures (issue-light variants NOT faster -> BW-bound).
//  - fp8 gather table: rejected by error arithmetic (absmax ~1.6 > 0.5).
//  - bucket-LDS accumulate: dead -- LDS fp-atomics serialize ~100+cyc/op on
//    gfx950 regardless of atomicAdd/unsafeAtomicAdd/relaxed-WG-scope (R10-12).
//  - direct global scatter build: 7.7x write-amplified (R4).
//  - build ~190us invariant across 4 implementations.

#define D_FEAT 128
#define D2     64          // feature pairs per row
#define SCAN_TILE 1024

#define PB 256             // partition/count blocks
#define PT 1024            // threads per partition/count block
#define RB_BITS 9          // rows per bucket = 512
#define ROWS_PER_BUCKET 512
#define COL_BITS 17        // N = 100000 < 2^17
#define CACHE_CAP 17152    // LDS edge cache entries (mean 16384, +6 sigma)

__device__ __forceinline__ uint32_t f2bf(float f) {
    uint32_t u = __float_as_uint(f);
    return (u + 0x7FFFu + ((u >> 16) & 1u)) >> 16;   // RNE
}
__device__ __forceinline__ float bf_lo(uint32_t w) { return __uint_as_float(w << 16); }
__device__ __forceinline__ float bf_hi(uint32_t w) { return __uint_as_float(w & 0xFFFF0000u); }

// ---------------- f32 -> bf16 conversion (2 elems/thread) ----------------
__global__ void convert_kernel(const float2* __restrict__ xin, uint32_t* __restrict__ xbf, int n2) {
    int i = blockIdx.x * blockDim.x + threadIdx.x;
    if (i < n2) {
        float2 f = xin[i];
        xbf[i] = f2bf(f.x) | (f2bf(f.y) << 16);
    }
}

// ---------------- phase 1: coarse per-(bucket,block) counts, LDS only ----------------
__global__ __launch_bounds__(PT) void coarse_count_kernel(const int* __restrict__ row,
                                                          int* __restrict__ cnt,
                                                          int E, int nbuck) {
    __shared__ int hist[256];
    const int t = threadIdx.x;
    if (t < 256) hist[t] = 0;
    __syncthreads();
    const int stride = PB * PT;
    const int gid = blockIdx.x * PT + t;
    const int E4 = E >> 2;
    const int4* __restrict__ r4 = (const int4*)row;
    for (int i = gid; i < E4; i += stride) {
        int4 r = r4[i];
        atomicAdd(&hist[r.x >> RB_BITS], 1);
        atomicAdd(&hist[r.y >> RB_BITS], 1);
        atomicAdd(&hist[r.z >> RB_BITS], 1);
        atomicAdd(&hist[r.w >> RB_BITS], 1);
    }
    for (int i = (E4 << 2) + gid; i < E; i += stride)   // tail (E%4 != 0)
        atomicAdd(&hist[row[i] >> RB_BITS], 1);
    __syncthreads();
    if (t < nbuck) cnt[t * PB + blockIdx.x] = hist[t];
}

// ---------------- scan phase 1: per-tile exclusive scan + tile sums ----------------
__global__ __launch_bounds__(SCAN_TILE) void scan1_kernel(const int* __restrict__ counts,
                                                          int* __restrict__ excl,
                                                          int* __restrict__ tileSums, int n) {
    __shared__ int wsum[16];
    const int tid  = threadIdx.x;
    const int lane = tid & 63;
    const int wave = tid >> 6;
    const int i    = blockIdx.x * SCAN_TILE + tid;

    int v = (i < n) ? counts[i] : 0;
    int incl = v;
    #pragma unroll
    for (int off = 1; off < 64; off <<= 1) {
        int t = __shfl_up(incl, off, 64);
        if (lane >= off) incl += t;
    }
    if (lane == 63) wsum[wave] = incl;
    __syncthreads();
    if (wave == 0) {
        int s = (lane < 16) ? wsum[lane] : 0;
        #pragma unroll
        for (int off = 1; off < 16; off <<= 1) {
            int t = __shfl_up(s, off, 64);
            if (lane >= off) s += t;
        }
        if (lane < 16) wsum[lane] = s;
    }
    __syncthreads();
    int wbase = (wave == 0) ? 0 : wsum[wave - 1];
    if (i < n) excl[i] = wbase + (incl - v);
    if (tid == 0) tileSums[blockIdx.x] = wsum[15];
}

// ---------------- scan phase 2: scan tile sums (single block) ----------------
__global__ __launch_bounds__(1024) void scan2_kernel(const int* __restrict__ tileSums,
                                                     int* __restrict__ tileBase,
                                                     int* __restrict__ total_out, int nb) {
    __shared__ int buf[1024];
    const int tid = threadIdx.x;
    int v = (tid < nb) ? tileSums[tid] : 0;
    buf[tid] = v;
    __syncthreads();
    #pragma unroll
    for (int off = 1; off < 1024; off <<= 1) {
        int t = (tid >= off) ? buf[tid - off] : 0;
        __syncthreads();
        buf[tid] += t;
        __syncthreads();
    }
    if (tid < nb) tileBase[tid] = buf[tid] - v;
    if (tid == nb - 1) *total_out = buf[tid];
}

// ---------------- phase 2: partition edges into coarse buckets (LDS cursors) ------
// 196 sequential write streams per block; 4 independent chains per iteration.
__global__ __launch_bounds__(PT) void partition_kernel(const int* __restrict__ row,
                                                       const int* __restrict__ col,
                                                       const float* __restrict__ val,
                                                       const int* __restrict__ cnt,
                                                       const int* __restrict__ tileBase,
                                                       int2* __restrict__ pack2,
                                                       int E, int nbuck) {
    __shared__ int cur[256];
    const int t = threadIdx.x;
    if (t < nbuck) {
        int idx = t * PB + blockIdx.x;
        cur[t] = cnt[idx] + tileBase[idx >> 10];
    }
    __syncthreads();
    const int stride = PB * PT;
    const int gid = blockIdx.x * PT + t;
    const int E4 = E >> 2;
    const int4*   __restrict__ r4 = (const int4*)row;
    const int4*   __restrict__ c4 = (const int4*)col;
    const float4* __restrict__ v4 = (const float4*)val;
    for (int i = gid; i < E4; i += stride) {
        int4   r = r4[i];
        int4   c = c4[i];
        float4 v = v4[i];
        int p0 = atomicAdd(&cur[r.x >> RB_BITS], 1);
        int p1 = atomicAdd(&cur[r.y >> RB_BITS], 1);
        int p2 = atomicAdd(&cur[r.z >> RB_BITS], 1);
        int p3 = atomicAdd(&cur[r.w >> RB_BITS], 1);
        pack2[p0] = make_int2(c.x | ((r.x & (ROWS_PER_BUCKET - 1)) << COL_BITS), __float_as_int(v.x));
        pack2[p1] = make_int2(c.y | ((r.y & (ROWS_PER_BUCKET - 1)) << COL_BITS), __float_as_int(v.y));
        pack2[p2] = make_int2(c.z | ((r.z & (ROWS_PER_BUCKET - 1)) << COL_BITS), __float_as_int(v.z));
        pack2[p3] = make_int2(c.w | ((r.w & (ROWS_PER_BUCKET - 1)) << COL_BITS), __float_as_int(v.w));
    }
    for (int i = (E4 << 2) + gid; i < E; i += stride) {  // tail
        int r = row[i];
        int pos = atomicAdd(&cur[r >> RB_BITS], 1);
        pack2[pos] = make_int2(col[i] | ((r & (ROWS_PER_BUCKET - 1)) << COL_BITS),
                               __float_as_int(val[i]));
    }
}

// ---------------- phase 3: per-bucket fine sort, LDS edge cache ----------------
__global__ __launch_bounds__(1024) void fine_sort_kernel(const int* __restrict__ cnt,
                                                         const int* __restrict__ tileBase,
                                                         const int2* __restrict__ pack2,
                                                         int2* __restrict__ pack,
                                                         int* __restrict__ offsets,
                                                         int E, int N, int nbuck) {
    extern __shared__ int2 ecache[];                  // CACHE_CAP entries
    __shared__ int buf[1024];
    __shared__ int cur[ROWS_PER_BUCKET];
    const int b = blockIdx.x;
    const int t = threadIdx.x;
    const int start = cnt[b << 8] + tileBase[b >> 2];
    const int end   = (b == nbuck - 1) ? E : (cnt[(b + 1) << 8] + tileBase[(b + 1) >> 2]);
    const int n  = end - start;
    const int nc = (n < CACHE_CAP) ? n : CACHE_CAP;

    for (int i = t; i < nc; i += 1024) ecache[i] = pack2[start + i];
    buf[t] = 0;
    __syncthreads();

    for (int i = t; i < n; i += 1024) {
        int key = (i < nc) ? ecache[i].x : pack2[start + i].x;
        atomicAdd(&buf[((unsigned)key) >> COL_BITS], 1);
    }
    __syncthreads();

    int v = buf[t];
    for (int off = 1; off < 1024; off <<= 1) {
        int tv = (t >= off) ? buf[t - off] : 0;
        __syncthreads();
        buf[t] += tv;
        __syncthreads();
    }
    int excl = buf[t] - v;
    if (t < ROWS_PER_BUCKET) {
        int r = (b << RB_BITS) + t;
        if (r < N) offsets[r] = start + excl;
        cur[t] = excl;
    }
    if (b == 0 && t == 0) offsets[N] = E;
    __syncthreads();

    for (int i = t; i < n; i += 1024) {
        int2 w = (i < nc) ? ecache[i] : pack2[start + i];
        int lr = ((unsigned)w.x) >> COL_BITS;
        int p = atomicAdd(&cur[lr], 1);               // LDS atomic
        pack[start + p] = make_int2(w.x & ((1 << COL_BITS) - 1), w.y);
    }
}

// ---------------- fused SpMM (bf16 gather) + scalar scale + ELU ----------------
// Block = 256 threads = 4 waves; wave owns one row.  The wave's 64 lanes split
// into 4 groups of 16: group g handles edge slot g of each 4-edge batch, lane
// loads 16B of the 256B source row via global_load_dwordx4 (1KB/instruction).
// Partial sums merged with two shfl_xor rounds at row end.
template <int OUT_BF16>
__global__ __launch_bounds__(256) void spmm_elu_kernel(
    const int* __restrict__ offsets, const int2* __restrict__ pack,
    const uint32_t* __restrict__ xin, void* __restrict__ xout,
    const float* __restrict__ scalars, int layer, int N) {
    const int wave = threadIdx.x >> 6;
    const int lane = threadIdx.x & 63;
    const int g    = lane >> 4;          // edge slot within a 4-edge batch
    const int sub  = lane & 15;          // 16B chunk within the source row
    const int r    = blockIdx.x * 4 + wave;
    if (r >= N) return;

    // wave-uniform -> SGPR so pack reads scalarize and the loop runs on SALU
    int e         = __builtin_amdgcn_readfirstlane(offsets[r]);
    const int end = __builtin_amdgcn_readfirstlane(offsets[r + 1]);

    const uint4* __restrict__ xin4 = (const uint4*)xin;   // row stride = 16 uint4

    float a[8];
    #pragma unroll
    for (int k = 0; k < 8; ++k) a[k] = 0.f;

    #define SEL4(PK, CO, VO)                                               \
        {                                                                  \
            int2 p0 = (PK)[0], p1 = (PK)[1], p2 = (PK)[2], p3 = (PK)[3];   \
            int cA = (g & 1) ? p1.x : p0.x, cB = (g & 1) ? p3.x : p2.x;    \
            int vA = (g & 1) ? p1.y : p0.y, vB = (g & 1) ? p3.y : p2.y;    \
            CO = (g & 2) ? cB : cA;                                        \
            VO = __int_as_float((g & 2) ? vB : vA);                        \
        }

    #define FMA8(W, V)                                                     \
        a[0] += (V) * bf_lo((W).x); a[1] += (V) * bf_hi((W).x);            \
        a[2] += (V) * bf_lo((W).y); a[3] += (V) * bf_hi((W).y);            \
        a[4] += (V) * bf_lo((W).z); a[5] += (V) * bf_hi((W).z);            \
        a[6] += (V) * bf_lo((W).w); a[7] += (V) * bf_hi((W).w);

    for (; e + 16 <= end; e += 16) {
        int c0, c1, c2, c3; float v0, v1, v2, v3;
        SEL4(pack + e,      c0, v0);
        SEL4(pack + e + 4,  c1, v1);
        SEL4(pack + e + 8,  c2, v2);
        SEL4(pack + e + 12, c3, v3);
        uint4 w0 = xin4[(((uint32_t)c0) << 4) + sub];
        uint4 w1 = xin4[(((uint32_t)c1) << 4) + sub];
        uint4 w2 = xin4[(((uint32_t)c2) << 4) + sub];
        uint4 w3 = xin4[(((uint32_t)c3) << 4) + sub];
        FMA8(w0, v0); FMA8(w1, v1); FMA8(w2, v2); FMA8(w3, v3);
    }
    for (; e + 4 <= end; e += 4) {
        int c0; float v0;
        SEL4(pack + e, c0, v0);
        uint4 w0 = xin4[(((uint32_t)c0) << 4) + sub];
        FMA8(w0, v0);
    }
    if (e < end) {                       // 1..3 leftover edges, pad with val=0
        const int rem = end - e;
        int2 pl = pack[end - 1];
        int2 p0 = pack[e];
        int2 p1 = (rem > 1) ? pack[e + 1] : make_int2(pl.x, 0);
        int2 p2 = (rem > 2) ? pack[e + 2] : make_int2(pl.x, 0);
        int2 p3 = make_int2(pl.x, 0);
        int cA = (g & 1) ? p1.x : p0.x, cB = (g & 1) ? p3.x : p2.x;
        int vA = (g & 1) ? p1.y : p0.y, vB = (g & 1) ? p3.y : p2.y;
        int c0 = (g & 2) ? cB : cA;
        float v0 = __int_as_float((g & 2) ? vB : vA);
        uint4 w0 = xin4[(((uint32_t)c0) << 4) + sub];
        FMA8(w0, v0);
    }
    #undef SEL4
    #undef FMA8

    // merge the 4 lane-group partials (same features live at same 'sub')
    #pragma unroll
    for (int off = 16; off <= 32; off <<= 1) {
        #pragma unroll
        for (int k = 0; k < 8; ++k) a[k] += __shfl_xor(a[k], off, 64);
    }

    const float s = scalars[layer];
    #pragma unroll
    for (int k = 0; k < 8; ++k) {
        float x = a[k] * s;
        a[k] = (x > 0.f) ? x : (expf(x) - 1.f);
    }

    if (OUT_BF16) {
        if (g == 0) {
            uint4 o;
            o.x = f2bf(a[0]) | (f2bf(a[1]) << 16);
            o.y = f2bf(a[2]) | (f2bf(a[3]) << 16);
            o.z = f2bf(a[4]) | (f2bf(a[5]) << 16);
            o.w = f2bf(a[6]) | (f2bf(a[7]) << 16);
            ((uint4*)xout)[(size_t)r * 16 + sub] = o;
        }
    } else {
        if (g == 0)
            ((float4*)xout)[(size_t)r * 32 + sub * 2]     = make_float4(a[0], a[1], a[2], a[3]);
        else if (g == 1)
            ((float4*)xout)[(size_t)r * 32 + sub * 2 + 1] = make_float4(a[4], a[5], a[6], a[7]);
    }
}

extern "C" void kernel_launch(void* const* d_in, const int* in_sizes, int n_in,
                              void* d_out, int out_size, void* d_ws, size_t ws_size,
                              hipStream_t stream) {
    const float* x         = (const float*)d_in[0];
    const int*   edge_row  = (const int*)d_in[1];
    const int*   edge_col  = (const int*)d_in[2];
    const float* edge_vals = (const float*)d_in[3];
    const float* scalars   = (const float*)d_in[4];

    const int N = in_sizes[0] / D_FEAT;                      // 100000
    const int E = in_sizes[1];                               // 3200000
    const int nbuck = (N + ROWS_PER_BUCKET - 1) >> RB_BITS;  // 196
    const int M = nbuck * PB;                                // 50176
    const int NB = (M + SCAN_TILE - 1) / SCAN_TILE;          // 49

    // ---- workspace bump allocator (256B aligned) ----
    char*  ws  = (char*)d_ws;
    size_t off = 0;
    auto alloc = [&](size_t bytes) -> void* {
        off = (off + 255) & ~(size_t)255;
        void* p = ws + off;
        off += bytes;
        return p;
    };
    int*      offsets  = (int*)alloc((size_t)(N + 1) * sizeof(int));
    int*      cnt      = (int*)alloc((size_t)(M + 1) * sizeof(int));
    int*      tileSums = (int*)alloc((size_t)NB * sizeof(int));
    int*      tileBase = (int*)alloc((size_t)NB * sizeof(int));
    int2*     pack2    = (int2*)alloc((size_t)E * sizeof(int2));
    int2*     pack     = (int2*)alloc((size_t)E * sizeof(int2));
    uint32_t* xbf      = (uint32_t*)alloc((size_t)N * D2 * sizeof(uint32_t));
    uint32_t* hbf      = (uint32_t*)pack2;   // alias: pack2 dead after fine_sort
    (void)ws_size;

    // ---- bf16 table + CSR build (no global atomics) ----
    convert_kernel<<<(N * D2 + 255) / 256, 256, 0, stream>>>((const float2*)x, xbf, N * D2);
    coarse_count_kernel<<<PB, PT, 0, stream>>>(edge_row, cnt, E, nbuck);
    scan1_kernel<<<NB, SCAN_TILE, 0, stream>>>(cnt, cnt, tileSums, M);
    scan2_kernel<<<1, 1024, 0, stream>>>(tileSums, tileBase, cnt + M, NB);
    partition_kernel<<<PB, PT, 0, stream>>>(edge_row, edge_col, edge_vals, cnt, tileBase,
                                            pack2, E, nbuck);
    fine_sort_kernel<<<nbuck, 1024, (size_t)CACHE_CAP * sizeof(int2), stream>>>(
        cnt, tileBase, pack2, pack, offsets, E, N, nbuck);

    // ---- layer 1: xbf -> hbf (bf16), layer 2: hbf -> d_out (f32) ----
    const int nblk = (N + 3) / 4;
    spmm_elu_kernel<1><<<nblk, 256, 0, stream>>>(offsets, pack, xbf, hbf, scalars, 0, N);
    spmm_elu_kernel<0><<<nblk, 256, 0, stream>>>(offsets, pack, hbf, (void*)d_out, scalars, 1, N);
}